// Round 5
// baseline (78.161 us; speedup 1.0000x reference)
//
#include <hip/hip_runtime.h>
#include <hip/hip_bf16.h>

// NT-Xent loss, MI355X. B=4096, D=256, N=8192, temp=0.5.
// R5: symmetry-halved Gram. sim is symmetric -> compute only tiles jtb>=itb.
// Full tiles (jtb>itb) contribute row-partials to rows I and col-partials to
// rows J (= row-sums of the skipped transpose tile). Diagonal 16x16 tiles
// contribute rows only (their transpose cells are inside the same tile).
// Grid = 528 blocks (bi<=bj pairs), block = 256 i-rows x 256 j-cols, 4 waves
// x 64 rows, A in regs (a[4][8]=128), B staged via global_load_lds
// (pre-swizzled source), double-buffered, NSTEP=4.
// zn pre-scaled by sqrt((1/T)*log2 e) so epilogue is bare exp2(acc);
// positive sim recovered as acc*ln2.

typedef __attribute__((ext_vector_type(4))) float f32x4;
typedef __attribute__((ext_vector_type(8))) short s16x8;

#define N_TOT 8192
#define B_HALF 4096
#define D_DIM 256
#define NSTEP 4
#define NBI 32                      // 32 i-tiles and 32 j-tiles of 256
#define NBLK (NBI * (NBI + 1) / 2)  // 528
#define SCL_PRE 1.6986436f          // sqrt(2.8853900817779268)
#define RES_SCALE 0.6931471805599453f  // ln2: acc*ln2 = dot*2/T*... = sim

__device__ inline unsigned short f2bf(float f) {
  __hip_bfloat16 h = __float2bfloat16(f);
  return *reinterpret_cast<unsigned short*>(&h);
}

__device__ inline float fexp2(float x) {
#if __has_builtin(__builtin_amdgcn_exp2f)
  return __builtin_amdgcn_exp2f(x);  // args in [-2.9, 2.9]
#else
  return exp2f(x);
#endif
}

__global__ __launch_bounds__(256) void nrm_kernel(const float* __restrict__ z1,
                                                  const float* __restrict__ z2,
                                                  unsigned short* __restrict__ zn) {
  int row = blockIdx.x * 4 + (threadIdx.x >> 6);
  int lane = threadIdx.x & 63;
  const float* src = (row < B_HALF) ? (z1 + (size_t)row * D_DIM)
                                    : (z2 + (size_t)(row - B_HALF) * D_DIM);
  f32x4 v = *reinterpret_cast<const f32x4*>(src + lane * 4);
  float ss = v.x * v.x + v.y * v.y + v.z * v.z + v.w * v.w;
#pragma unroll
  for (int m = 32; m >= 1; m >>= 1) ss += __shfl_xor(ss, m);
  float inv = SCL_PRE / fmaxf(sqrtf(ss), 1e-8f);  // normalize + exp2 prescale
  ushort4 o;
  o.x = f2bf(v.x * inv);
  o.y = f2bf(v.y * inv);
  o.z = f2bf(v.z * inv);
  o.w = f2bf(v.w * inv);
  *reinterpret_cast<ushort4*>(zn + (size_t)row * D_DIM + lane * 4) = o;
}

__global__ __launch_bounds__(256, 2) void gram_kernel(const unsigned short* __restrict__ zn,
                                                      float* __restrict__ part,
                                                      float* __restrict__ ppos) {
  __shared__ __align__(16) char bt[2 * 64 * 512];  // double-buffered B tiles
  __shared__ float colLDS[4][256];                 // per-wave col partials
  const int tid = threadIdx.x;
  const int w = tid >> 6, l = tid & 63;
  const int lm = l & 15, hh = l >> 4;

  // decode linear block index -> (bi <= bj) pair
  const int idx = blockIdx.x;
  int bj = (int)((sqrtf(8.f * (float)idx + 1.f) - 1.f) * 0.5f);
  while ((bj + 1) * (bj + 2) / 2 <= idx) ++bj;
  while (bj * (bj + 1) / 2 > idx) --bj;
  const int bi = idx - bj * (bj + 1) / 2;

  const int r0w = bi * 256 + w * 64;  // this wave's 64 i-rows
  const int jbase = bj * 256;
  const char* znb = reinterpret_cast<const char*>(zn);

  auto stage = [&](int s, int bfi) {
    const char* gs = znb + (size_t)(jbase + s * 64) * 512;
    char* ldsbase = bt + bfi * 32768 + (w * 16) * 512;
#pragma unroll
    for (int q = 0; q < 8; ++q) {
      int rloc = w * 16 + q * 2 + (l >> 5);
      const char* g = gs + (size_t)rloc * 512 + (((l & 31) * 16) ^ ((rloc & 7) << 4));
      __builtin_amdgcn_global_load_lds(
          (const __attribute__((address_space(1))) void*)g,
          (__attribute__((address_space(3))) void*)(ldsbase + q * 1024), 16, 0, 0);
    }
  };

  stage(0, 0);

  s16x8 a[4][8];
#pragma unroll
  for (int rf = 0; rf < 4; ++rf)
#pragma unroll
    for (int g = 0; g < 8; ++g)
      a[rf][g] = *reinterpret_cast<const s16x8*>(
          znb + (size_t)(r0w + rf * 16 + lm) * 512 + g * 64 + hh * 16);

  float sume[4][4];
#pragma unroll
  for (int rf = 0; rf < 4; ++rf)
#pragma unroll
    for (int t = 0; t < 4; ++t) sume[rf][t] = 0.f;

  const int swz = (lm & 7) << 4;
  const bool self = true;  // placeholder to keep diff small (unused)
  (void)self;

  for (int s = 0; s < NSTEP; ++s) {
    __syncthreads();
    if (s + 1 < NSTEP) stage(s + 1, (s + 1) & 1);
    const char* bp = bt + (s & 1) * 32768;

#pragma unroll
    for (int jt = 0; jt < 4; ++jt) {
      const char* br = bp + (jt * 16 + lm) * 512;
      f32x4 ac[4];
#pragma unroll
      for (int rf = 0; rf < 4; ++rf) ac[rf] = (f32x4){0.f, 0.f, 0.f, 0.f};
      __builtin_amdgcn_s_setprio(1);
#pragma unroll
      for (int g = 0; g < 8; ++g) {
        s16x8 bf = *reinterpret_cast<const s16x8*>(br + ((g * 64 + hh * 16) ^ swz));
        ac[0] = __builtin_amdgcn_mfma_f32_16x16x32_bf16(a[0][g], bf, ac[0], 0, 0, 0);
        ac[1] = __builtin_amdgcn_mfma_f32_16x16x32_bf16(a[1][g], bf, ac[1], 0, 0, 0);
        ac[2] = __builtin_amdgcn_mfma_f32_16x16x32_bf16(a[2][g], bf, ac[2], 0, 0, 0);
        ac[3] = __builtin_amdgcn_mfma_f32_16x16x32_bf16(a[3][g], bf, ac[3], 0, 0, 0);
      }
      __builtin_amdgcn_s_setprio(0);
      const int jtb = jbase + s * 64 + jt * 16;
      float csum = 0.f;
#pragma unroll
      for (int rf = 0; rf < 4; ++rf) {
        const int itb = r0w + rf * 16;
        if (jtb < itb) continue;  // transpose tile handled via col-partials
        if (jtb == itb) {         // diagonal tile: rows only, mask self
#pragma unroll
          for (int t = 0; t < 4; ++t) {
            float e = fexp2(ac[rf][t]);
            if (lm == hh * 4 + t) e = 0.f;  // C/D map: row=hh*4+t, col=lm
            sume[rf][t] += e;
          }
        } else {  // full upper tile: rows + cols (+ positive pair)
          const bool ps = ((itb ^ B_HALF) == jtb);
#pragma unroll
          for (int t = 0; t < 4; ++t) {
            float sv = ac[rf][t];
            float e = fexp2(sv);
            sume[rf][t] += e;
            csum += e;
            if (ps && (lm == hh * 4 + t)) {  // sim symmetric: fill both halves
              ppos[itb + hh * 4 + t] = sv * RES_SCALE;
              ppos[jtb + lm] = sv * RES_SCALE;
            }
          }
        }
      }
      // column partials -> rows jtb+lm; each (s,jt) owns distinct columns
      csum += __shfl_xor(csum, 16);
      csum += __shfl_xor(csum, 32);
      if (hh == 0) colLDS[w][s * 64 + jt * 16 + lm] = csum;
    }
  }

  // row partials: reduce across the 16 lm lanes sharing each row
#pragma unroll
  for (int rf = 0; rf < 4; ++rf)
#pragma unroll
    for (int t = 0; t < 4; ++t) {
      float v = sume[rf][t];
#pragma unroll
      for (int m = 1; m < 16; m <<= 1) v += __shfl_xor(v, m);
      if (lm == 0) part[(size_t)bj * N_TOT + r0w + rf * 16 + hh * 4 + t] = v;
    }

  // column partials: combine 4 waves, slot 32+bi (disjoint j-range per bj)
  __syncthreads();
  float cs = colLDS[0][tid] + colLDS[1][tid] + colLDS[2][tid] + colLDS[3][tid];
  part[(size_t)(NBI + bi) * N_TOT + jbase + tid] = cs;
}

__global__ __launch_bounds__(256) void fin1_kernel(const float* __restrict__ part,
                                                   const float* __restrict__ ppos,
                                                   float* __restrict__ partial) {
  int i = blockIdx.x * 256 + threadIdx.x;
  float se = 0.f;
#pragma unroll
  for (int s = 0; s < 2 * NBI; ++s) se += part[(size_t)s * N_TOT + i];
  float acc = logf(se) - ppos[i];
#pragma unroll
  for (int m = 32; m >= 1; m >>= 1) acc += __shfl_xor(acc, m);
  __shared__ float red[4];
  if ((threadIdx.x & 63) == 0) red[threadIdx.x >> 6] = acc;
  __syncthreads();
  if (threadIdx.x == 0) partial[blockIdx.x] = red[0] + red[1] + red[2] + red[3];
}

__global__ void fin2_kernel(const float* __restrict__ partial, float* __restrict__ out) {
  float v = (threadIdx.x < 32) ? partial[threadIdx.x] : 0.f;
#pragma unroll
  for (int m = 32; m >= 1; m >>= 1) v += __shfl_xor(v, m);
  if (threadIdx.x == 0) out[0] = v / (float)N_TOT;
}

extern "C" void kernel_launch(void* const* d_in, const int* in_sizes, int n_in,
                              void* d_out, int out_size, void* d_ws, size_t ws_size,
                              hipStream_t stream) {
  const float* z1 = (const float*)d_in[0];
  const float* z2 = (const float*)d_in[1];
  float* out = (float*)d_out;
  char* ws = (char*)d_ws;

  unsigned short* zn = (unsigned short*)ws;                // 4 MiB
  float* part = (float*)(ws + (size_t)N_TOT * D_DIM * 2);  // 64*8192 f32 = 2 MiB
  float* ppos = part + (size_t)2 * NBI * N_TOT;            // 8192 f32
  float* partial = ppos + N_TOT;                           // 32 f32

  hipMemsetAsync(part, 0, (size_t)2 * NBI * N_TOT * sizeof(float), stream);
  nrm_kernel<<<N_TOT / 4, 256, 0, stream>>>(z1, z2, zn);
  gram_kernel<<<NBLK, 256, 0, stream>>>(zn, part, ppos);
  fin1_kernel<<<N_TOT / 256, 256, 0, stream>>>(part, ppos, partial);
  fin2_kernel<<<1, 64, 0, stream>>>(partial, out);
}

// Round 6
// 50.744 us; speedup vs baseline: 1.5403x; 1.5403x over previous
//
#include <hip/hip_runtime.h>
#include <hip/hip_bf16.h>

// NT-Xent loss, MI355X. B=4096, D=256, N=8192, temp=0.5.
// normalize(+exp2 prescale) -> bf16 zn -> MFMA Gram with fused exp/LSE
// partials -> finalize. R6 = R4 structure + deferred (software-pipelined)
// epilogue: the exp/sum VALU work of tile jt-1 runs while tile jt's ds_reads
// are in flight, before its MFMA cluster -> MFMA/VALU/LDS overlap within a
// wave (R4/R5 counters showed the three pipes were running back-to-back:
// dur ~= MFMA + LDS + VALU serial sum, MfmaUtil 29%).
// gram: block = 256 i-rows x 512 j-cols, 4 waves x 64 rows, A in regs
// (a[4][8]=128), B staged via global_load_lds (pre-swizzled source, linear
// LDS dest), double-buffered. __launch_bounds__(256,2): live set ~210 fits
// the 256-reg tier (R2's spill came from the since-removed unroll-2).

typedef __attribute__((ext_vector_type(4))) float f32x4;
typedef __attribute__((ext_vector_type(8))) short s16x8;

#define N_TOT 8192
#define B_HALF 4096
#define D_DIM 256
#define JSPLIT 16
#define JCOLS 512
#define NSTEP 8
#define SCL_PRE 1.6986436f             // sqrt((1/T)*log2 e) = sqrt(2.8853901)
#define RES_SCALE 0.6931471805599453f  // ln2: sim = acc * ln2 after prescale

__device__ inline unsigned short f2bf(float f) {
  __hip_bfloat16 h = __float2bfloat16(f);
  return *reinterpret_cast<unsigned short*>(&h);
}

__device__ inline float fexp2(float x) {
#if __has_builtin(__builtin_amdgcn_exp2f)
  return __builtin_amdgcn_exp2f(x);  // raw v_exp_f32; args in [-2.9, 2.9]
#else
  return exp2f(x);
#endif
}

__global__ __launch_bounds__(256) void nrm_kernel(const float* __restrict__ z1,
                                                  const float* __restrict__ z2,
                                                  unsigned short* __restrict__ zn) {
  int row = blockIdx.x * 4 + (threadIdx.x >> 6);
  int lane = threadIdx.x & 63;
  const float* src = (row < B_HALF) ? (z1 + (size_t)row * D_DIM)
                                    : (z2 + (size_t)(row - B_HALF) * D_DIM);
  f32x4 v = *reinterpret_cast<const f32x4*>(src + lane * 4);
  float ss = v.x * v.x + v.y * v.y + v.z * v.z + v.w * v.w;
#pragma unroll
  for (int m = 32; m >= 1; m >>= 1) ss += __shfl_xor(ss, m);
  float inv = SCL_PRE / fmaxf(sqrtf(ss), 1e-8f);  // normalize + exp2 prescale
  ushort4 o;
  o.x = f2bf(v.x * inv);
  o.y = f2bf(v.y * inv);
  o.z = f2bf(v.z * inv);
  o.w = f2bf(v.w * inv);
  *reinterpret_cast<ushort4*>(zn + (size_t)row * D_DIM + lane * 4) = o;
}

__global__ __launch_bounds__(256, 2) void gram_kernel(const unsigned short* __restrict__ zn,
                                                      float* __restrict__ psum,
                                                      float* __restrict__ ppos) {
  __shared__ __align__(16) char bt[2 * 64 * 512];  // double-buffered 64-row B tiles
  const int tid = threadIdx.x;
  const int w = tid >> 6, l = tid & 63;
  const int lm = l & 15, hh = l >> 4;
  const int r0w = blockIdx.x * 256 + w * 64;  // this wave's 64 i-rows
  const int jbase = blockIdx.y * JCOLS;
  const char* znb = reinterpret_cast<const char*>(zn);

  // stage step s (64 B-rows) into buffer bi. LDS dest linear (lane*16);
  // swizzle realized by XOR-permuting the global source within each 512B row.
  auto stage = [&](int s, int bi) {
    const char* gs = znb + (size_t)(jbase + s * 64) * 512;
    char* ldsbase = bt + bi * 32768 + (w * 16) * 512;
#pragma unroll
    for (int q = 0; q < 8; ++q) {
      int rloc = w * 16 + q * 2 + (l >> 5);
      const char* g = gs + (size_t)rloc * 512 + (((l & 31) * 16) ^ ((rloc & 7) << 4));
      __builtin_amdgcn_global_load_lds(
          (const __attribute__((address_space(1))) void*)g,
          (__attribute__((address_space(3))) void*)(ldsbase + q * 1024), 16, 0, 0);
    }
  };

  stage(0, 0);  // prefetch first tile; overlaps the A-fragment loads below

  // A fragments: 64 rows x K=256 in registers. lane: row lm (+rf*16), k-bytes
  // g*64 + hh*16 .. +15 (8 bf16). Same layout as B frags (Gram symmetry).
  s16x8 a[4][8];
#pragma unroll
  for (int rf = 0; rf < 4; ++rf)
#pragma unroll
    for (int g = 0; g < 8; ++g)
      a[rf][g] = *reinterpret_cast<const s16x8*>(
          znb + (size_t)(r0w + rf * 16 + lm) * 512 + g * 64 + hh * 16);

  float sume[4][4];
#pragma unroll
  for (int rf = 0; rf < 4; ++rf)
#pragma unroll
    for (int t = 0; t < 4; ++t) sume[rf][t] = 0.f;

  const int swz = (lm & 7) << 4;

  // deferred-epilogue state: accumulators of the PREVIOUS 16-col tile
  f32x4 pac[4];
  int pjtb = -1;

  // epilogue of a finished tile: exp + LSE partial + diag mask + positive
  auto epilogue = [&](int jtb) {
#pragma unroll
    for (int rf = 0; rf < 4; ++rf) {
      const int itb = r0w + rf * 16;
      const bool dg = (itb == jtb);
      const bool ps = ((itb ^ B_HALF) == jtb);
      if (dg | ps) {  // wave-uniform; at most 8 of 128 tiles per wave
#pragma unroll
        for (int t = 0; t < 4; ++t) {
          float sv = pac[rf][t];
          float e = fexp2(sv);
          bool self = (lm == hh * 4 + t);  // C/D map: row=hh*4+t, col=lm
          if (dg && self) e = 0.f;         // mask diagonal
          sume[rf][t] += e;
          if (ps && self) ppos[itb + hh * 4 + t] = sv * RES_SCALE;
        }
      } else {
#pragma unroll
        for (int t = 0; t < 4; ++t) sume[rf][t] += fexp2(pac[rf][t]);
      }
    }
  };

  for (int s = 0; s < NSTEP; ++s) {
    __syncthreads();  // drains my stage loads (vmcnt0) + all waves done w/ prev buf
    if (s + 1 < NSTEP) stage(s + 1, (s + 1) & 1);  // async prefetch under compute
    const char* bp = bt + (s & 1) * 32768;

#pragma unroll
    for (int jt = 0; jt < 4; ++jt) {
      const char* br = bp + (jt * 16 + lm) * 512;
      // previous tile's VALU epilogue runs here: independent of this tile's
      // ds_reads, so it fills their latency (and other-wave MFMA time)
      if (pjtb >= 0) epilogue(pjtb);
      f32x4 ac[4];
#pragma unroll
      for (int rf = 0; rf < 4; ++rf) ac[rf] = (f32x4){0.f, 0.f, 0.f, 0.f};
      __builtin_amdgcn_s_setprio(1);
#pragma unroll
      for (int g = 0; g < 8; ++g) {
        s16x8 bf = *reinterpret_cast<const s16x8*>(br + ((g * 64 + hh * 16) ^ swz));
        ac[0] = __builtin_amdgcn_mfma_f32_16x16x32_bf16(a[0][g], bf, ac[0], 0, 0, 0);
        ac[1] = __builtin_amdgcn_mfma_f32_16x16x32_bf16(a[1][g], bf, ac[1], 0, 0, 0);
        ac[2] = __builtin_amdgcn_mfma_f32_16x16x32_bf16(a[2][g], bf, ac[2], 0, 0, 0);
        ac[3] = __builtin_amdgcn_mfma_f32_16x16x32_bf16(a[3][g], bf, ac[3], 0, 0, 0);
      }
      __builtin_amdgcn_s_setprio(0);
#pragma unroll
      for (int rf = 0; rf < 4; ++rf) pac[rf] = ac[rf];
      pjtb = jbase + s * 64 + jt * 16;
    }
  }
  epilogue(pjtb);  // drain the last tile

  // reduce partial sums across the 16 lanes (lm) sharing each row
#pragma unroll
  for (int rf = 0; rf < 4; ++rf)
#pragma unroll
    for (int t = 0; t < 4; ++t) {
      float v = sume[rf][t];
#pragma unroll
      for (int m = 1; m < 16; m <<= 1) v += __shfl_xor(v, m);
      if (lm == 0) psum[(size_t)blockIdx.y * N_TOT + r0w + rf * 16 + hh * 4 + t] = v;
    }
}

__global__ __launch_bounds__(256) void fin1_kernel(const float* __restrict__ psum,
                                                   const float* __restrict__ ppos,
                                                   float* __restrict__ partial) {
  int i = blockIdx.x * 256 + threadIdx.x;
  float se = 0.f;
#pragma unroll
  for (int s = 0; s < JSPLIT; ++s) se += psum[(size_t)s * N_TOT + i];
  float acc = logf(se) - ppos[i];
#pragma unroll
  for (int m = 32; m >= 1; m >>= 1) acc += __shfl_xor(acc, m);
  __shared__ float red[4];
  if ((threadIdx.x & 63) == 0) red[threadIdx.x >> 6] = acc;
  __syncthreads();
  if (threadIdx.x == 0) partial[blockIdx.x] = red[0] + red[1] + red[2] + red[3];
}

__global__ void fin2_kernel(const float* __restrict__ partial, float* __restrict__ out) {
  float v = (threadIdx.x < 32) ? partial[threadIdx.x] : 0.f;
#pragma unroll
  for (int m = 32; m >= 1; m >>= 1) v += __shfl_xor(v, m);
  if (threadIdx.x == 0) out[0] = v / (float)N_TOT;
}

extern "C" void kernel_launch(void* const* d_in, const int* in_sizes, int n_in,
                              void* d_out, int out_size, void* d_ws, size_t ws_size,
                              hipStream_t stream) {
  const float* z1 = (const float*)d_in[0];
  const float* z2 = (const float*)d_in[1];
  float* out = (float*)d_out;
  char* ws = (char*)d_ws;

  unsigned short* zn = (unsigned short*)ws;                 // 4 MiB
  float* psum = (float*)(ws + (size_t)N_TOT * D_DIM * 2);   // 16*8192 f32 = 512 KiB
  float* ppos = psum + (size_t)JSPLIT * N_TOT;              // 8192 f32
  float* partial = ppos + N_TOT;                            // 32 f32

  nrm_kernel<<<N_TOT / 4, 256, 0, stream>>>(z1, z2, zn);
  gram_kernel<<<dim3(N_TOT / 256, JSPLIT), 256, 0, stream>>>(zn, psum, ppos);
  fin1_kernel<<<N_TOT / 256, 256, 0, stream>>>(psum, ppos, partial);
  fin2_kernel<<<1, 64, 0, stream>>>(partial, out);
}